// Round 3
// baseline (120.478 us; speedup 1.0000x reference)
//
#include <hip/hip_runtime.h>

// FeatureEmbedder: out[b, f*64+d] = relu(x[b,f] * W[f,d] + b[f,d])
// x: [16384, 128] f32, W: [128, 64] f32, b: [128, 64] f32
// out: [16384, 8192] f32  (512 MB -> HBM-write-bound)
//
// R2: nontemporal float4 stores via native ext_vector_type (HIP_vector_type
// float4 is rejected by __builtin_nontemporal_store). Streaming 512 MB has
// zero reuse -> bypass L2 ownership/pollution. Unroll 8 for store pipelining.

#define BATCH 16384
#define NFEAT 128
#define EMBD  64
#define ROW4  (NFEAT * EMBD / 4)   // 2048 float4 per output row
#define FEAT4 (EMBD / 4)           // 16 float4 per feature

typedef float vfloat4 __attribute__((ext_vector_type(4)));

__global__ __launch_bounds__(256) void feature_embed_kernel(
    const float* __restrict__ x,
    const vfloat4* __restrict__ W4,
    const vfloat4* __restrict__ B4,
    vfloat4* __restrict__ out4) {

    const int gtid = blockIdx.x * blockDim.x + threadIdx.x;  // 0 .. 524287
    const int col4 = gtid & (ROW4 - 1);   // loop-invariant column (float4 units)
    int row        = gtid >> 11;          // starting row, 0..255
    const int f    = col4 >> 4;           // feature index for this column

    // W/b are tiny (32 KB each) and column is fixed per thread -> hoist loads.
    const vfloat4 w  = W4[col4];
    const vfloat4 bb = B4[col4];
    const float* xp = x + f;

    #pragma unroll 8
    for (; row < BATCH; row += 256) {
        const float xv = xp[row << 7];    // x[row, f] (16B/wave, L2-resident)
        vfloat4 o;
        o.x = fmaxf(fmaf(xv, w.x, bb.x), 0.0f);
        o.y = fmaxf(fmaf(xv, w.y, bb.y), 0.0f);
        o.z = fmaxf(fmaf(xv, w.z, bb.z), 0.0f);
        o.w = fmaxf(fmaf(xv, w.w, bb.w), 0.0f);
        // Streaming store: 64 lanes x 16 B = 1 KB coalesced, nontemporal.
        __builtin_nontemporal_store(o, &out4[(row << 11) + col4]);
    }
}

extern "C" void kernel_launch(void* const* d_in, const int* in_sizes, int n_in,
                              void* d_out, int out_size, void* d_ws, size_t ws_size,
                              hipStream_t stream) {
    const float*   x  = (const float*)d_in[0];
    const vfloat4* W4 = (const vfloat4*)d_in[1];
    const vfloat4* B4 = (const vfloat4*)d_in[2];
    vfloat4* out4     = (vfloat4*)d_out;

    // 2048 blocks x 256 threads = 524288 threads = 256 rows of float4s.
    // Grid stride is a multiple of the row width, so each thread's column
    // (and thus its W/b fragment) is fixed for the whole kernel.
    feature_embed_kernel<<<2048, 256, 0, stream>>>(x, W4, B4, out4);
}